// Round 4
// baseline (316.834 us; speedup 1.0000x reference)
//
#include <hip/hip_runtime.h>
#include <stdint.h>

#define D_IN  128
#define D_OUT 64
#define BN_EPS 1e-3f

#define BIN_SHIFT 6
#define BIN_NODES 64           // 1 << BIN_SHIFT
#define BIN_CAP   2560         // avg 2048 records/bin, +11 sigma headroom
#define CHUNK     8192         // edges per partition block (391 blocks)
#define MAX_BINS  1600
#define STAT_SLICES 64

typedef __attribute__((ext_vector_type(8))) short bf16x8;
typedef __attribute__((ext_vector_type(4))) float f32x4;

__device__ __forceinline__ ushort f32_to_bf16_rne(float f) {
  uint u = __float_as_uint(f);
  u += 0x7FFFu + ((u >> 16) & 1u);
  return (ushort)(u >> 16);
}
__device__ __forceinline__ float bf16_to_f32(ushort h) {
  return __uint_as_float((uint)h << 16);
}

// ------------- GEMM via MFMA: pre16 = bf16(X @ W), bf16 in / fp32 acc -------
// Row-major pre16[row][64ch]: one node = one 128-B cache line (load-bearing
// for the gather; slab layouts over-fetch 4x on random access — round 1).
__global__ __launch_bounds__(256) void gemm_mfma_kernel(
    const float* __restrict__ x, const float* __restrict__ W,
    ushort* __restrict__ pre16, int n_nodes, int n_tiles) {
  __shared__ ushort Wb[D_IN * D_OUT];  // 16 KB bf16 copy of W
  const int t = threadIdx.x;
  for (int i = t; i < D_IN * D_OUT; i += 256) Wb[i] = f32_to_bf16_rne(W[i]);
  __syncthreads();

  const int lane = t & 63;
  const int wave = t >> 6;
  const int m = lane & 15;
  const int quad = lane >> 4;

  bf16x8 bfrag[4][4];
#pragma unroll
  for (int nt = 0; nt < 4; ++nt)
#pragma unroll
    for (int s = 0; s < 4; ++s)
#pragma unroll
      for (int j = 0; j < 8; ++j)
        bfrag[nt][s][j] =
            (short)Wb[(32 * s + quad * 8 + j) * D_OUT + nt * 16 + m];

  for (int tile = blockIdx.x; tile < n_tiles; tile += gridDim.x) {
    const int rbase = tile * 64 + wave * 16;
    const int row = rbase + m;
    const size_t rl = (size_t)min(row, n_nodes - 1);
    f32x4 acc0 = {0.f, 0.f, 0.f, 0.f}, acc1 = {0.f, 0.f, 0.f, 0.f};
    f32x4 acc2 = {0.f, 0.f, 0.f, 0.f}, acc3 = {0.f, 0.f, 0.f, 0.f};
#pragma unroll
    for (int s = 0; s < 4; ++s) {
      const float4 xa = *(const float4*)&x[rl * D_IN + s * 32 + quad * 8];
      const float4 xb = *(const float4*)&x[rl * D_IN + s * 32 + quad * 8 + 4];
      bf16x8 af;
      af[0] = (short)f32_to_bf16_rne(xa.x);
      af[1] = (short)f32_to_bf16_rne(xa.y);
      af[2] = (short)f32_to_bf16_rne(xa.z);
      af[3] = (short)f32_to_bf16_rne(xa.w);
      af[4] = (short)f32_to_bf16_rne(xb.x);
      af[5] = (short)f32_to_bf16_rne(xb.y);
      af[6] = (short)f32_to_bf16_rne(xb.z);
      af[7] = (short)f32_to_bf16_rne(xb.w);
      acc0 = __builtin_amdgcn_mfma_f32_16x16x32_bf16(af, bfrag[0][s], acc0, 0, 0, 0);
      acc1 = __builtin_amdgcn_mfma_f32_16x16x32_bf16(af, bfrag[1][s], acc1, 0, 0, 0);
      acc2 = __builtin_amdgcn_mfma_f32_16x16x32_bf16(af, bfrag[2][s], acc2, 0, 0, 0);
      acc3 = __builtin_amdgcn_mfma_f32_16x16x32_bf16(af, bfrag[3][s], acc3, 0, 0, 0);
    }
#pragma unroll
    for (int reg = 0; reg < 4; ++reg) {
      const int r = rbase + quad * 4 + reg;
      if (r < n_nodes) {
        ushort* po = &pre16[(size_t)r * D_OUT + m];
        po[0]  = f32_to_bf16_rne(acc0[reg]);
        po[16] = f32_to_bf16_rne(acc1[reg]);
        po[32] = f32_to_bf16_rne(acc2[reg]);
        po[48] = f32_to_bf16_rne(acc3[reg]);
      }
    }
  }
}

// ---------------- Partition: bin edges by dst>>6, x4-vectorized loads ---------
// record: w0 = (dst_low6 << 17) | src17 ; w1 = fp32 edge_val
__global__ __launch_bounds__(256) void partition_kernel(
    const float* __restrict__ ev, const int* __restrict__ esrc,
    const int* __restrict__ edst, int* __restrict__ bin_cursor,
    uint2* __restrict__ bucket, int n_edges, int n_bins) {
  __shared__ int cnt[MAX_BINS];
  __shared__ int base[MAX_BINS];
  const int t = threadIdx.x;
  const int beg = blockIdx.x * CHUNK;
  const int end = min(beg + CHUNK, n_edges);

  for (int i = t; i < n_bins; i += 256) cnt[i] = 0;
  __syncthreads();

  // phase A: histogram, 4 edges per lane per load (1 KB/wave coalesced)
  for (int i = beg + t * 4; i < end; i += 1024) {
    if (i + 3 < end) {
      const int4 d4 = *(const int4*)&edst[i];
      atomicAdd(&cnt[d4.x >> BIN_SHIFT], 1);
      atomicAdd(&cnt[d4.y >> BIN_SHIFT], 1);
      atomicAdd(&cnt[d4.z >> BIN_SHIFT], 1);
      atomicAdd(&cnt[d4.w >> BIN_SHIFT], 1);
    } else {
      for (int k = i; k < end; ++k) atomicAdd(&cnt[edst[k] >> BIN_SHIFT], 1);
    }
  }
  __syncthreads();

  // phase B: reserve contiguous space per (block, bin)
  for (int i = t; i < n_bins; i += 256) {
    const int c = cnt[i];
    int b = 0;
    if (c > 0) b = atomicAdd(&bin_cursor[i], c);
    if (b > BIN_CAP) b = BIN_CAP;
    base[i] = i * BIN_CAP + b;
    cnt[i] = 0;  // reuse as rank cursor
  }
  __syncthreads();

  // phase C: scatter records (re-reads are L2-hot from phase A)
  for (int i = beg + t * 4; i < end; i += 1024) {
    if (i + 3 < end) {
      const int4 d4 = *(const int4*)&edst[i];
      const int4 s4 = *(const int4*)&esrc[i];
      const float4 v4 = *(const float4*)&ev[i];
#pragma unroll
      for (int k = 0; k < 4; ++k) {
        const int dst = (&d4.x)[k];
        const int src = (&s4.x)[k];
        const float v = (&v4.x)[k];
        const int bin = dst >> BIN_SHIFT;
        const int r = atomicAdd(&cnt[bin], 1);
        const int pos = base[bin] + r;
        if (pos < (bin + 1) * BIN_CAP) {
          const uint w0 = ((uint)(dst & (BIN_NODES - 1)) << 17) | (uint)src;
          bucket[pos] = make_uint2(w0, __float_as_uint(v));
        }
      }
    } else {
      for (int k = i; k < end; ++k) {
        const int dst = edst[k];
        const int bin = dst >> BIN_SHIFT;
        const int r = atomicAdd(&cnt[bin], 1);
        const int pos = base[bin] + r;
        if (pos < (bin + 1) * BIN_CAP) {
          const uint w0 = ((uint)(dst & (BIN_NODES - 1)) << 17) | (uint)esrc[k];
          bucket[pos] = make_uint2(w0, __float_as_uint(ev[k]));
        }
      }
    }
  }
}

// ------- Kernel A: LDS counting sort per bin, write sorted records in place --
// Round-3 lesson: one-bin-per-block gather caps machine fill at 76% (400K
// work-threads vs 524K capacity) regardless of block shape. So the sort now
// only SORTS: records go back to bucket[] (in place, sorted by node) as
// (src, val_f32), and seg[node] = (start,end) global indices. The gather moves
// to a wave-per-node kernel with no LDS binding.
__global__ __launch_bounds__(256) void bin_sort_kernel(
    uint2* __restrict__ bucket, const int* __restrict__ bin_cursor,
    int2* __restrict__ seg, int n_nodes) {
  __shared__ uint s_src[BIN_CAP];          // 10 KB
  __shared__ uint s_val[BIN_CAP];          // 10 KB (f32 bits, no rounding)
  __shared__ int s_hist[BIN_NODES];
  __shared__ int s_off[BIN_NODES + 1];
  __shared__ int s_cur[BIN_NODES];

  const int t = threadIdx.x;
  const int bin = blockIdx.x;
  const int cnt = min(bin_cursor[bin], BIN_CAP);
  const int64_t rbase = (int64_t)bin * BIN_CAP;

  if (t < BIN_NODES) s_hist[t] = 0;
  __syncthreads();

  for (int i = t; i < cnt; i += 256)
    atomicAdd(&s_hist[bucket[rbase + i].x >> 17], 1);
  __syncthreads();

  int own = (t < BIN_NODES) ? s_hist[t] : 0;
  for (int off = 1; off < BIN_NODES; off <<= 1) {
    int u = 0;
    if (t < BIN_NODES && t >= off) u = s_hist[t - off];
    __syncthreads();
    if (t < BIN_NODES) s_hist[t] += u;
    __syncthreads();
  }
  if (t < BIN_NODES) {
    const int e = s_hist[t] - own;
    s_off[t] = e;
    s_cur[t] = e;
  }
  if (t == 0) s_off[BIN_NODES] = cnt;
  __syncthreads();

  for (int i = t; i < cnt; i += 256) {
    const uint2 r = bucket[rbase + i];
    const int d = r.x >> 17;
    const int p = atomicAdd(&s_cur[d], 1);
    s_src[p] = r.x & 0x1FFFFu;
    s_val[p] = r.y;
  }
  __syncthreads();  // all bucket reads for this bin complete -> safe in-place

  for (int i = t; i < cnt; i += 256)
    bucket[rbase + i] = make_uint2(s_src[i], s_val[i]);

  if (t < BIN_NODES) {
    const int node = bin * BIN_NODES + t;
    if (node < n_nodes)
      seg[node] = make_int2((int)rbase + s_off[t], (int)rbase + s_off[t + 1]);
  }
}

// ------- Kernel B: wave-per-node gather, full-machine TLP --------------------
// 25000 blocks x 4 waves; each wave streams its node's sorted records
// (broadcast 8-B loads, L1-hot: one 128-B line covers 16 records) and runs the
// proven 8-deep half-wave gather pipeline against pre16. Stats are sliced
// 64-way to avoid 25000-deep atomic serialization per address.
__global__ __launch_bounds__(256) void gather_kernel(
    const ushort* __restrict__ pre16, const uint2* __restrict__ srec,
    const int2* __restrict__ seg, float* __restrict__ out,
    float* __restrict__ stats, int n_nodes) {
  __shared__ float red[4 * 64];
  __shared__ float red2[4 * 64];

  const int t = threadIdx.x;
  const int lane = t & 63;
  const int wave = t >> 6;
  const int half = lane >> 5;
  const int hl = lane & 31;
  const int node = blockIdx.x * 4 + wave;
  float csx = 0.f, csy = 0.f, cs2x = 0.f, cs2y = 0.f;

  if (node < n_nodes) {
    const int2 se = seg[node];
    const int je = se.y;
    float a0x = 0.f, a0y = 0.f, a1x = 0.f, a1y = 0.f;
    float a2x = 0.f, a2y = 0.f, a3x = 0.f, a3y = 0.f;
    float a4x = 0.f, a4y = 0.f, a5x = 0.f, a5y = 0.f;
    float a6x = 0.f, a6y = 0.f, a7x = 0.f, a7y = 0.f;
    int j = se.x + half;
    // main: 16 records per wave-iteration, 8 gather loads in flight per half
    for (; j + 14 < je; j += 16) {
      const uint2 r0 = srec[j],      r1 = srec[j + 2];
      const uint2 r2 = srec[j + 4],  r3 = srec[j + 6];
      const uint2 r4 = srec[j + 8],  r5 = srec[j + 10];
      const uint2 r6 = srec[j + 12], r7 = srec[j + 14];
      const uint p0 = *(const uint*)&pre16[(size_t)r0.x * D_OUT + 2 * hl];
      const uint p1 = *(const uint*)&pre16[(size_t)r1.x * D_OUT + 2 * hl];
      const uint p2 = *(const uint*)&pre16[(size_t)r2.x * D_OUT + 2 * hl];
      const uint p3 = *(const uint*)&pre16[(size_t)r3.x * D_OUT + 2 * hl];
      const uint p4 = *(const uint*)&pre16[(size_t)r4.x * D_OUT + 2 * hl];
      const uint p5 = *(const uint*)&pre16[(size_t)r5.x * D_OUT + 2 * hl];
      const uint p6 = *(const uint*)&pre16[(size_t)r6.x * D_OUT + 2 * hl];
      const uint p7 = *(const uint*)&pre16[(size_t)r7.x * D_OUT + 2 * hl];
      const float v0 = __uint_as_float(r0.y), v1 = __uint_as_float(r1.y);
      const float v2 = __uint_as_float(r2.y), v3 = __uint_as_float(r3.y);
      const float v4 = __uint_as_float(r4.y), v5 = __uint_as_float(r5.y);
      const float v6 = __uint_as_float(r6.y), v7 = __uint_as_float(r7.y);
      a0x += v0 * bf16_to_f32((ushort)(p0 & 0xFFFFu));
      a0y += v0 * bf16_to_f32((ushort)(p0 >> 16));
      a1x += v1 * bf16_to_f32((ushort)(p1 & 0xFFFFu));
      a1y += v1 * bf16_to_f32((ushort)(p1 >> 16));
      a2x += v2 * bf16_to_f32((ushort)(p2 & 0xFFFFu));
      a2y += v2 * bf16_to_f32((ushort)(p2 >> 16));
      a3x += v3 * bf16_to_f32((ushort)(p3 & 0xFFFFu));
      a3y += v3 * bf16_to_f32((ushort)(p3 >> 16));
      a4x += v4 * bf16_to_f32((ushort)(p4 & 0xFFFFu));
      a4y += v4 * bf16_to_f32((ushort)(p4 >> 16));
      a5x += v5 * bf16_to_f32((ushort)(p5 & 0xFFFFu));
      a5y += v5 * bf16_to_f32((ushort)(p5 >> 16));
      a6x += v6 * bf16_to_f32((ushort)(p6 & 0xFFFFu));
      a6y += v6 * bf16_to_f32((ushort)(p6 >> 16));
      a7x += v7 * bf16_to_f32((ushort)(p7 & 0xFFFFu));
      a7y += v7 * bf16_to_f32((ushort)(p7 >> 16));
    }
    // mid: 8 records per wave-iteration
    for (; j + 6 < je; j += 8) {
      const uint2 r0 = srec[j],     r1 = srec[j + 2];
      const uint2 r2 = srec[j + 4], r3 = srec[j + 6];
      const uint p0 = *(const uint*)&pre16[(size_t)r0.x * D_OUT + 2 * hl];
      const uint p1 = *(const uint*)&pre16[(size_t)r1.x * D_OUT + 2 * hl];
      const uint p2 = *(const uint*)&pre16[(size_t)r2.x * D_OUT + 2 * hl];
      const uint p3 = *(const uint*)&pre16[(size_t)r3.x * D_OUT + 2 * hl];
      const float v0 = __uint_as_float(r0.y), v1 = __uint_as_float(r1.y);
      const float v2 = __uint_as_float(r2.y), v3 = __uint_as_float(r3.y);
      a0x += v0 * bf16_to_f32((ushort)(p0 & 0xFFFFu));
      a0y += v0 * bf16_to_f32((ushort)(p0 >> 16));
      a1x += v1 * bf16_to_f32((ushort)(p1 & 0xFFFFu));
      a1y += v1 * bf16_to_f32((ushort)(p1 >> 16));
      a2x += v2 * bf16_to_f32((ushort)(p2 & 0xFFFFu));
      a2y += v2 * bf16_to_f32((ushort)(p2 >> 16));
      a3x += v3 * bf16_to_f32((ushort)(p3 & 0xFFFFu));
      a3y += v3 * bf16_to_f32((ushort)(p3 >> 16));
    }
    for (; j < je; j += 2) {
      const uint2 r = srec[j];
      const float v = __uint_as_float(r.y);
      const uint p = *(const uint*)&pre16[(size_t)r.x * D_OUT + 2 * hl];
      a0x += v * bf16_to_f32((ushort)(p & 0xFFFFu));
      a0y += v * bf16_to_f32((ushort)(p >> 16));
    }
    float ax = ((a0x + a1x) + (a2x + a3x)) + ((a4x + a5x) + (a6x + a7x));
    float ay = ((a0y + a1y) + (a2y + a3y)) + ((a4y + a5y) + (a6y + a7y));
    ax += __shfl_xor(ax, 32);   // merge odd-record half into even half
    ay += __shfl_xor(ay, 32);
    if (half == 0) {
      *(float2*)&out[(size_t)node * D_OUT + 2 * hl] = make_float2(ax, ay);
      csx = ax;
      cs2x = ax * ax;
      csy = ay;
      cs2y = ay * ay;
    }
  }

  if (half == 0) {  // zeros for invalid nodes keep the reduction correct
    red[wave * 64 + 2 * hl] = csx;
    red[wave * 64 + 2 * hl + 1] = csy;
    red2[wave * 64 + 2 * hl] = cs2x;
    red2[wave * 64 + 2 * hl + 1] = cs2y;
  }
  __syncthreads();
  if (t < 64) {
    const float s = red[t] + red[64 + t] + red[128 + t] + red[192 + t];
    const float s2 = red2[t] + red2[64 + t] + red2[128 + t] + red2[192 + t];
    const int sl = (blockIdx.x & (STAT_SLICES - 1)) * 128;
    atomicAdd(&stats[sl + t], s);
    atomicAdd(&stats[sl + 64 + t], s2);
  }
}

// ---------------- fold the 64 stat slices into one 128-float vector ----------
__global__ __launch_bounds__(128) void stats_reduce_kernel(
    const float* __restrict__ stats, float* __restrict__ sfinal) {
  const int c = threadIdx.x;
  float s = 0.f;
#pragma unroll 8
  for (int sl = 0; sl < STAT_SLICES; ++sl) s += stats[sl * 128 + c];
  sfinal[c] = s;
}

// ---------------- Normalize + ReLU (in place, float4) ----------------
__global__ __launch_bounds__(256) void norm_kernel(
    float* __restrict__ out, const float* __restrict__ stats, int64_t n_vec4,
    float inv_n) {
  const int c = (threadIdx.x * 4) & 63;
  float mean[4], scale[4];
#pragma unroll
  for (int k = 0; k < 4; ++k) {
    mean[k] = stats[c + k] * inv_n;
    const float var = stats[64 + c + k] * inv_n - mean[k] * mean[k];
    scale[k] = rsqrtf(var + BN_EPS);
  }
  const int64_t stride = (int64_t)gridDim.x * 256;
  for (int64_t i = (int64_t)blockIdx.x * 256 + threadIdx.x; i < n_vec4;
       i += stride) {
    float4 v = ((float4*)out)[i];
    v.x = (v.x - mean[0]) * scale[0];
    v.y = (v.y - mean[1]) * scale[1];
    v.z = (v.z - mean[2]) * scale[2];
    v.w = (v.w - mean[3]) * scale[3];
    v.x = v.x > 0.f ? v.x : 0.f;
    v.y = v.y > 0.f ? v.y : 0.f;
    v.z = v.z > 0.f ? v.z : 0.f;
    v.w = v.w > 0.f ? v.w : 0.f;
    ((float4*)out)[i] = v;
  }
}

// ---------------- launch ----------------
extern "C" void kernel_launch(void* const* d_in, const int* in_sizes, int n_in,
                              void* d_out, int out_size, void* d_ws,
                              size_t ws_size, hipStream_t stream) {
  const float* x = (const float*)d_in[0];
  const float* W = (const float*)d_in[1];
  const float* ev = (const float*)d_in[2];
  const int* esrc = (const int*)d_in[3];
  const int* edst = (const int*)d_in[4];

  const int n_nodes = in_sizes[0] / D_IN;
  const int n_edges = in_sizes[2];
  const int64_t n_out = (int64_t)n_nodes * D_OUT;
  const int n_bins = (n_nodes + BIN_NODES - 1) >> BIN_SHIFT;
  const int n_row_tiles = (n_nodes + 63) / 64;

  float* out = (float*)d_out;

  // workspace layout
  char* w = (char*)d_ws;
  ushort* pre16 = (ushort*)w;             w += (size_t)n_nodes * D_OUT * 2;
  int* bin_cursor = (int*)w;              w += (size_t)n_bins * 4;
  float* stats = (float*)w;               w += (size_t)STAT_SLICES * 128 * 4;
  float* sfinal = (float*)w;              w += 128 * 4;
  w = (char*)(((uintptr_t)w + 7) & ~(uintptr_t)7);
  int2* seg = (int2*)w;                   w += (size_t)n_nodes * 8;
  uint2* bucket = (uint2*)w;              // n_bins * BIN_CAP * 8 bytes (~32 MB)

  hipMemsetAsync(bin_cursor, 0, (size_t)n_bins * 4, stream);
  hipMemsetAsync(stats, 0, (size_t)STAT_SLICES * 128 * 4, stream);

  gemm_mfma_kernel<<<(n_row_tiles + 1) / 2, 256, 0, stream>>>(
      x, W, pre16, n_nodes, n_row_tiles);
  partition_kernel<<<(n_edges + CHUNK - 1) / CHUNK, 256, 0, stream>>>(
      ev, esrc, edst, bin_cursor, bucket, n_edges, n_bins);
  bin_sort_kernel<<<n_bins, 256, 0, stream>>>(bucket, bin_cursor, seg, n_nodes);
  gather_kernel<<<(n_nodes + 3) / 4, 256, 0, stream>>>(pre16, bucket, seg, out,
                                                       stats, n_nodes);
  stats_reduce_kernel<<<1, 128, 0, stream>>>(stats, sfinal);
  norm_kernel<<<2048, 256, 0, stream>>>(out, sfinal, n_out / 4,
                                        1.0f / (float)n_nodes);
}